// Round 9
// baseline (1290.164 us; speedup 1.0000x reference)
//
#include <hip/hip_runtime.h>

typedef unsigned short u16;
typedef unsigned int u32;

#define N_NODES 64000
#define DIM 64
#define NGRAPH 320
#define NPG 200
#define NEDGE 1024000
#define EPG 3200
#define NSTEPS 5
#define NITERS 6
#define NT 208  // 13 tiles of 16 nodes

typedef __attribute__((ext_vector_type(8))) short bf16x8;
typedef __attribute__((ext_vector_type(4))) float f32x4;

__device__ __forceinline__ float bf2f(u16 u) {
  u32 x = ((u32)u) << 16;
  float f;
  __builtin_memcpy(&f, &x, 4);
  return f;
}
__device__ __forceinline__ u16 f2bf(float f) {
  u32 x;
  __builtin_memcpy(&x, &f, 4);
  x = (x + 0x7FFFu + ((x >> 16) & 1u)) >> 16;
  return (u16)x;
}
__device__ __forceinline__ float sigmf(float x) { return 1.0f / (1.0f + __expf(-x)); }

// ---------------- prep kernels ----------------

// CSR with 6 per-etype sections per graph. rec = src_local (u16).
// rows[g] = flat prefix array ro[0..6*NPG] (1201 ints); bounds for (t,n) are
// [ro[t*NPG+n], ro[t*NPG+n+1]).
__global__ void __launch_bounds__(256) k_csr6(const int* __restrict__ src,
                                              const int* __restrict__ dst,
                                              const int* __restrict__ ety,
                                              u16* __restrict__ recs,
                                              int* __restrict__ rows) {
  __shared__ int cnt[6 * NPG];
  __shared__ int ro[6 * NPG + 1];
  int g = blockIdx.x, tid = threadIdx.x;
  int base = g * NPG;
  for (int i = tid; i < 6 * NPG; i += 256) cnt[i] = 0;
  __syncthreads();
  for (int e = tid; e < EPG; e += 256) {
    int d = dst[g * EPG + e] - base;
    int t = ety[g * EPG + e];
    atomicAdd(&cnt[t * NPG + d], 1);
  }
  __syncthreads();
  if (tid == 0) {
    int s = 0;
    for (int i = 0; i < 6 * NPG; i++) { ro[i] = s; s += cnt[i]; }
    ro[6 * NPG] = s;  // == EPG
  }
  __syncthreads();
  for (int i = tid; i < 6 * NPG; i += 256) cnt[i] = ro[i];
  __syncthreads();
  for (int e = tid; e < EPG; e += 256) {
    int d = dst[g * EPG + e] - base;
    int t = ety[g * EPG + e];
    int s = src[g * EPG + e] - base;
    int pos = atomicAdd(&cnt[t * NPG + d], 1);
    recs[g * EPG + pos] = (u16)s;
  }
  for (int i = tid; i <= 6 * NPG; i += 256) rows[g * (6 * NPG + 1) + i] = ro[i];
}

__global__ void k_cvt(const float* __restrict__ src, u16* __restrict__ dst, int n) {
  int i = blockIdx.x * 256 + threadIdx.x;
  if (i < n) dst[i] = f2bf(src[i]);
}

// transpose fp32 [R][C] -> bf16 [C][R]
__global__ void k_tcvt(const float* __restrict__ src, u16* __restrict__ dst, int R, int C) {
  int i = blockIdx.x * 256 + threadIdx.x;
  if (i < R * C) {
    int r = i / C, c = i - r * C;
    dst[c * R + r] = f2bf(src[i]);
  }
}

// W_edge [t][k][o] fp32 -> WeT [t][o][k] bf16
__global__ void k_cvt_weT(const float* __restrict__ W_edge, u16* __restrict__ WeT) {
  int i = blockIdx.x * 256 + threadIdx.x;
  if (i < 6 * 64 * 64) {
    int t = i >> 12, rem = i & 4095;
    int o = rem >> 6, k = rem & 63;
    WeT[i] = f2bf(W_edge[t * 4096 + k * 64 + o]);
  }
}

// ---------------- fused GGNN + Set2Set mega-kernel ----------------
// One block per graph; all 5 steps + readout in LDS.

__global__ void __launch_bounds__(512, 2) k_ggnn(
    const float* __restrict__ feats,
    const u16* __restrict__ WeT, const float* __restrict__ b_edge,
    const u16* __restrict__ Wihb, const u16* __restrict__ Whhb,
    const float* __restrict__ gb_ih, const float* __restrict__ gb_hh,
    const u16* __restrict__ recs, const int* __restrict__ rows,
    const u16* __restrict__ WTih0b, const u16* __restrict__ WThh0b,
    const u16* __restrict__ WTih1b, const u16* __restrict__ WThh1b,
    const u16* __restrict__ WTih2b, const u16* __restrict__ WThh2b,
    const float* __restrict__ b_ih0, const float* __restrict__ b_hh0,
    const float* __restrict__ b_ih1, const float* __restrict__ b_hh1,
    const float* __restrict__ b_ih2, const float* __restrict__ b_hh2,
    const float* __restrict__ Wp, const float* __restrict__ bp,
    float* __restrict__ out) {
  __shared__ float h_s[NPG * 64];        // 51,200 B  (fp32 state; feat for readout)
  __shared__ u16 hb_s[NT * 64];          // 26,624 B  (bf16 state, padded)
  __shared__ u16 wh_s[NT * 64];          // 26,624 B  (per-etype Wh; then ab)
  __shared__ u16 rec_s[EPG];             //  6,400 B
  __shared__ int row_s[6 * NPG + 1];     //  4,804 B
  // set2set scratch
  __shared__ float qstar[128];
  __shared__ float xbuf[64];
  __shared__ float hs2[3][64];
  __shared__ float cs2[3][64];
  __shared__ float gates[256];
  __shared__ float gpart[2 * 256];
  __shared__ float e_s2[NPG];
  __shared__ float red[8][64];
  __shared__ float scal[2];

  int g = blockIdx.x;
  int tid = threadIdx.x;
  int lane = tid & 63, w = tid >> 6;
  int m = lane & 15, quad = lane >> 4;

  // ---- init: h, hb from feats; edges; rows ----
  for (int i = tid; i < NPG * 64; i += 512) {
    float v = feats[(size_t)g * NPG * 64 + i];
    h_s[i] = v;
    hb_s[i] = f2bf(v);
  }
  for (int i = NPG * 64 + tid; i < NT * 64; i += 512) hb_s[i] = 0;
  {
    const u32* r32 = (const u32*)(recs + g * EPG);
    u32* rs32 = (u32*)rec_s;
    for (int i = tid; i < EPG / 2; i += 512) rs32[i] = r32[i];
  }
  for (int i = tid; i <= 6 * NPG; i += 512) row_s[i] = rows[g * (6 * NPG + 1) + i];

  float acc[25];
#pragma unroll
  for (int q = 0; q < 25; q++) acc[q] = 0.f;

  // GRU biases per lane (d = dq*16 + m)
  float bir[4], bhr[4], biz[4], bhz[4], bin_[4], bhn[4];
#pragma unroll
  for (int dq = 0; dq < 4; dq++) {
    int d = dq * 16 + m;
    bir[dq] = gb_ih[d];        bhr[dq] = gb_hh[d];
    biz[dq] = gb_ih[64 + d];   bhz[dq] = gb_hh[64 + d];
    bin_[dq] = gb_ih[128 + d]; bhn[dq] = gb_hh[128 + d];
  }

  for (int step = 0; step < NSTEPS; step++) {
    // ---- 6 phases: Wh(etype t) -> wh_s; CSR gather into acc regs ----
    for (int t = 0; t < 6; t++) {
      __syncthreads();  // prior readers of wh_s done
      for (int tile = w; tile < 13; tile += 8) {
        const u16* ap = hb_s + (tile * 16 + m) * 64 + quad * 8;
        bf16x8 a0 = *(const bf16x8*)ap;
        bf16x8 a1 = *(const bf16x8*)(ap + 32);
#pragma unroll
        for (int ot = 0; ot < 4; ot++) {
          const u16* bp2 = WeT + ((t * 64 + ot * 16 + m) * 64) + quad * 8;
          bf16x8 b0 = *(const bf16x8*)bp2;
          bf16x8 b1 = *(const bf16x8*)(bp2 + 32);
          f32x4 c = {0.f, 0.f, 0.f, 0.f};
          c = __builtin_amdgcn_mfma_f32_16x16x32_bf16(a0, b0, c, 0, 0, 0);
          c = __builtin_amdgcn_mfma_f32_16x16x32_bf16(a1, b1, c, 0, 0, 0);
          float bias = b_edge[t * 64 + ot * 16 + m];
#pragma unroll
          for (int r = 0; r < 4; r++) {
            wh_s[(tile * 16 + quad * 4 + r) * 64 + ot * 16 + m] = f2bf(c[r] + bias);
          }
        }
      }
      __syncthreads();
      const int* row = row_s + t * NPG;
      for (int q = 0; q < 25; q++) {
        int n = q * 8 + w;
        int rs = row[n], re = row[n + 1];
        float r = 0.f;
        int e = rs;
        for (; e + 2 <= re; e += 2) {
          int s0 = rec_s[e], s1 = rec_s[e + 1];
          r += bf2f(wh_s[s0 * 64 + lane]) + bf2f(wh_s[s1 * 64 + lane]);
        }
        for (; e < re; e++) r += bf2f(wh_s[(int)rec_s[e] * 64 + lane]);
        acc[q] += r;
      }
    }
    __syncthreads();  // all scatter reads of wh_s done
    // ---- ab into wh_s (reuse); zero pad rows ----
    for (int q = 0; q < 25; q++) {
      int n = q * 8 + w;
      wh_s[n * 64 + lane] = f2bf(acc[q]);
      acc[q] = 0.f;
    }
    for (int i = NPG * 64 + tid; i < NT * 64; i += 512) wh_s[i] = 0;
    __syncthreads();
    // ---- GRU (register accumulators; epilogue writes h_s/hb_s own rows) ----
    for (int tile = w; tile < 13; tile += 8) {
      const u16* aap = wh_s + (tile * 16 + m) * 64 + quad * 8;
      const u16* ahp = hb_s + (tile * 16 + m) * 64 + quad * 8;
      bf16x8 aa0 = *(const bf16x8*)aap;
      bf16x8 aa1 = *(const bf16x8*)(aap + 32);
      bf16x8 ah0 = *(const bf16x8*)ahp;
      bf16x8 ah1 = *(const bf16x8*)(ahp + 32);
      f32x4 ci[12], ch[12];
#pragma unroll
      for (int jt = 0; jt < 12; jt++) {
        const u16* bip = Wihb + (jt * 16 + m) * 64 + quad * 8;
        const u16* bhp = Whhb + (jt * 16 + m) * 64 + quad * 8;
        bf16x8 bi0 = *(const bf16x8*)bip;
        bf16x8 bi1 = *(const bf16x8*)(bip + 32);
        bf16x8 bh0 = *(const bf16x8*)bhp;
        bf16x8 bh1 = *(const bf16x8*)(bhp + 32);
        f32x4 z4 = {0.f, 0.f, 0.f, 0.f};
        ci[jt] = __builtin_amdgcn_mfma_f32_16x16x32_bf16(aa0, bi0, z4, 0, 0, 0);
        ci[jt] = __builtin_amdgcn_mfma_f32_16x16x32_bf16(aa1, bi1, ci[jt], 0, 0, 0);
        ch[jt] = __builtin_amdgcn_mfma_f32_16x16x32_bf16(ah0, bh0, z4, 0, 0, 0);
        ch[jt] = __builtin_amdgcn_mfma_f32_16x16x32_bf16(ah1, bh1, ch[jt], 0, 0, 0);
      }
#pragma unroll
      for (int r = 0; r < 4; r++) {
        int node = tile * 16 + quad * 4 + r;
        if (node < NPG) {
#pragma unroll
          for (int dq = 0; dq < 4; dq++) {
            int d = dq * 16 + m;
            float rr = sigmf(ci[dq][r] + ch[dq][r] + bir[dq] + bhr[dq]);
            float zz = sigmf(ci[4 + dq][r] + ch[4 + dq][r] + biz[dq] + bhz[dq]);
            float nn = tanhf(ci[8 + dq][r] + bin_[dq] + rr * (ch[8 + dq][r] + bhn[dq]));
            float hv = h_s[node * 64 + d];
            float hn = (1.0f - zz) * nn + zz * hv;
            h_s[node * 64 + d] = hn;
            hb_s[node * 64 + d] = f2bf(hn);
          }
        }
      }
    }
  }
  __syncthreads();

  // ---------------- Set2Set (feat = h_s) ----------------
  int j = tid & 255, part = tid >> 8;
  int wid = w;
  if (tid < 128) qstar[tid] = 0.f;
  if (tid < 64) {
    xbuf[tid] = 0.f;
    for (int l = 0; l < 3; l++) { hs2[l][tid] = 0.f; cs2[l][tid] = 0.f; }
  }
  __syncthreads();
  for (int it = 0; it < NITERS; it++) {
    {
      float a2 = 0.f;
      if (part == 0) {
#pragma unroll 8
        for (int k = 0; k < 96; k++) a2 += qstar[k] * bf2f(WTih0b[k * 256 + j]);
      } else {
#pragma unroll 8
        for (int k = 96; k < 128; k++) a2 += qstar[k] * bf2f(WTih0b[k * 256 + j]);
#pragma unroll 8
        for (int k = 0; k < 64; k++) a2 += hs2[0][k] * bf2f(WThh0b[k * 256 + j]);
      }
      gpart[part * 256 + j] = a2;
    }
    __syncthreads();
    if (tid < 256) gates[tid] = gpart[tid] + gpart[256 + tid] + b_ih0[tid] + b_hh0[tid];
    __syncthreads();
    if (tid < 64) {
      float c = sigmf(gates[64 + tid]) * cs2[0][tid] + sigmf(gates[tid]) * tanhf(gates[128 + tid]);
      float x = sigmf(gates[192 + tid]) * tanhf(c);
      cs2[0][tid] = c; hs2[0][tid] = x; xbuf[tid] = x;
    }
    __syncthreads();
    for (int l = 1; l < 3; l++) {
      const u16* Wi = (l == 1) ? WTih1b : WTih2b;
      const u16* Wh = (l == 1) ? WThh1b : WThh2b;
      const float* bi = (l == 1) ? b_ih1 : b_ih2;
      const float* bh = (l == 1) ? b_hh1 : b_hh2;
      const u16* W = part ? Wh : Wi;
      const float* xv = part ? hs2[l] : xbuf;
      float a2 = 0.f;
#pragma unroll 8
      for (int k = 0; k < 64; k++) a2 += xv[k] * bf2f(W[k * 256 + j]);
      gpart[part * 256 + j] = a2;
      __syncthreads();
      if (tid < 256) gates[tid] = gpart[tid] + gpart[256 + tid] + bi[tid] + bh[tid];
      __syncthreads();
      if (tid < 64) {
        float c = sigmf(gates[64 + tid]) * cs2[l][tid] + sigmf(gates[tid]) * tanhf(gates[128 + tid]);
        float x = sigmf(gates[192 + tid]) * tanhf(c);
        cs2[l][tid] = c; hs2[l][tid] = x; xbuf[tid] = x;
      }
      __syncthreads();
    }
    for (int n = wid; n < NPG; n += 8) {
      float v = h_s[n * 64 + lane] * xbuf[lane];
      for (int off = 32; off > 0; off >>= 1) v += __shfl_down(v, off);
      if (lane == 0) e_s2[n] = v;
    }
    __syncthreads();
    if (tid < 64) {
      float mx = -1e30f;
      for (int n = lane; n < NPG; n += 64) mx = fmaxf(mx, e_s2[n]);
      for (int off = 32; off > 0; off >>= 1) mx = fmaxf(mx, __shfl_down(mx, off));
      mx = __shfl(mx, 0);
      float ssum = 0.f;
      for (int n = lane; n < NPG; n += 64) {
        float ex = __expf(e_s2[n] - mx);
        e_s2[n] = ex;
        ssum += ex;
      }
      for (int off = 32; off > 0; off >>= 1) ssum += __shfl_down(ssum, off);
      if (lane == 0) scal[0] = ssum;
    }
    __syncthreads();
    float denom = scal[0];
    {
      float r = 0.f;
      for (int n = wid; n < NPG; n += 8) r += h_s[n * 64 + lane] * e_s2[n];
      red[wid][lane] = r;
    }
    __syncthreads();
    if (tid < 64) {
      float ro = 0.f;
#pragma unroll
      for (int ww = 0; ww < 8; ww++) ro += red[ww][lane];
      qstar[lane] = xbuf[lane];
      qstar[64 + lane] = ro / denom;
    }
    __syncthreads();
  }
  if (tid < 3) {
    float s = bp[tid];
    for (int k = 0; k < 128; k++) s += qstar[k] * Wp[tid * 128 + k];
    out[g * 3 + tid] = s;
  }
}

// ---------------- host ----------------

extern "C" void kernel_launch(void* const* d_in, const int* in_sizes, int n_in,
                              void* d_out, int out_size, void* d_ws, size_t ws_size,
                              hipStream_t stream) {
  const float* feats  = (const float*)d_in[0];
  const float* W_edge = (const float*)d_in[1];
  const float* b_edge = (const float*)d_in[2];
  const float* gWih   = (const float*)d_in[3];
  const float* gWhh   = (const float*)d_in[4];
  const float* gbih   = (const float*)d_in[5];
  const float* gbhh   = (const float*)d_in[6];
  const float* lWi0   = (const float*)d_in[7];
  const float* lWh0   = (const float*)d_in[8];
  const float* lbi0   = (const float*)d_in[9];
  const float* lbh0   = (const float*)d_in[10];
  const float* lWi1   = (const float*)d_in[11];
  const float* lWh1   = (const float*)d_in[12];
  const float* lbi1   = (const float*)d_in[13];
  const float* lbh1   = (const float*)d_in[14];
  const float* lWi2   = (const float*)d_in[15];
  const float* lWh2   = (const float*)d_in[16];
  const float* lbi2   = (const float*)d_in[17];
  const float* lbh2   = (const float*)d_in[18];
  const float* Wp     = (const float*)d_in[19];
  const float* bp     = (const float*)d_in[20];
  const int* src      = (const int*)d_in[21];
  const int* dst      = (const int*)d_in[22];
  const int* ety      = (const int*)d_in[23];
  float* out = (float*)d_out;

  char* ws = (char*)d_ws;
  u16* recs   = (u16*)ws;                        // 2,048,000 B
  int* rows   = (int*)(ws + 2048000);            // 1,537,280 B
  u16* WeTb   = (u16*)(ws + 3585280);            //    49,152 B
  u16* Wihb   = (u16*)(ws + 3634432);            //    24,576 B
  u16* Whhb   = (u16*)(ws + 3659008);            //    24,576 B
  u16* WTih0b = (u16*)(ws + 3683584);            //    65,536 B
  u16* WThh0b = WTih0b + 32768;                  //    32,768 B
  u16* WTih1b = WThh0b + 16384;
  u16* WThh1b = WTih1b + 16384;
  u16* WTih2b = WThh1b + 16384;
  u16* WThh2b = WTih2b + 16384;

  k_csr6<<<NGRAPH, 256, 0, stream>>>(src, dst, ety, recs, rows);
  k_cvt_weT<<<96, 256, 0, stream>>>(W_edge, WeTb);
  k_cvt<<<48, 256, 0, stream>>>(gWih, Wihb, 12288);
  k_cvt<<<48, 256, 0, stream>>>(gWhh, Whhb, 12288);
  k_tcvt<<<128, 256, 0, stream>>>(lWi0, WTih0b, 256, 128);
  k_tcvt<<<64, 256, 0, stream>>>(lWh0, WThh0b, 256, 64);
  k_tcvt<<<64, 256, 0, stream>>>(lWi1, WTih1b, 256, 64);
  k_tcvt<<<64, 256, 0, stream>>>(lWh1, WThh1b, 256, 64);
  k_tcvt<<<64, 256, 0, stream>>>(lWi2, WTih2b, 256, 64);
  k_tcvt<<<64, 256, 0, stream>>>(lWh2, WThh2b, 256, 64);

  k_ggnn<<<NGRAPH, 512, 0, stream>>>(
      feats, WeTb, b_edge, Wihb, Whhb, gbih, gbhh, recs, rows,
      WTih0b, WThh0b, WTih1b, WThh1b, WTih2b, WThh2b,
      lbi0, lbh0, lbi1, lbh1, lbi2, lbh2, Wp, bp, out);
}

// Round 11
// 1257.738 us; speedup vs baseline: 1.0258x; 1.0258x over previous
//
#include <hip/hip_runtime.h>

typedef unsigned short u16;
typedef unsigned int u32;

#define N_NODES 64000
#define DIM 64
#define NGRAPH 320
#define NPG 200
#define NEDGE 1024000
#define EPG 3200
#define NSTEPS 5
#define NITERS 6
#define WSTR 72   // u16 row stride for bf16 tiles (bank-conflict padding)
#define HSTR 65   // float row stride for h_s

typedef __attribute__((ext_vector_type(8))) short bf16x8;
typedef __attribute__((ext_vector_type(4))) float f32x4;

__device__ __forceinline__ float bf2f(u16 u) {
  u32 x = ((u32)u) << 16;
  float f;
  __builtin_memcpy(&f, &x, 4);
  return f;
}
__device__ __forceinline__ u16 f2bf(float f) {
  u32 x;
  __builtin_memcpy(&x, &f, 4);
  x = (x + 0x7FFFu + ((x >> 16) & 1u)) >> 16;
  return (u16)x;
}
__device__ __forceinline__ float sigmf(float x) { return 1.0f / (1.0f + __expf(-x)); }

// ---------------- prep kernels ----------------

__global__ void __launch_bounds__(256) k_csr6(const int* __restrict__ src,
                                              const int* __restrict__ dst,
                                              const int* __restrict__ ety,
                                              u16* __restrict__ recs,
                                              int* __restrict__ rows) {
  __shared__ int cnt[6 * NPG];
  __shared__ int ro[6 * NPG + 1];
  int g = blockIdx.x, tid = threadIdx.x;
  int base = g * NPG;
  for (int i = tid; i < 6 * NPG; i += 256) cnt[i] = 0;
  __syncthreads();
  for (int e = tid; e < EPG; e += 256) {
    int d = dst[g * EPG + e] - base;
    int t = ety[g * EPG + e];
    atomicAdd(&cnt[t * NPG + d], 1);
  }
  __syncthreads();
  if (tid == 0) {
    int s = 0;
    for (int i = 0; i < 6 * NPG; i++) { ro[i] = s; s += cnt[i]; }
    ro[6 * NPG] = s;  // == EPG
  }
  __syncthreads();
  for (int i = tid; i < 6 * NPG; i += 256) cnt[i] = ro[i];
  __syncthreads();
  for (int e = tid; e < EPG; e += 256) {
    int d = dst[g * EPG + e] - base;
    int t = ety[g * EPG + e];
    int s = src[g * EPG + e] - base;
    int pos = atomicAdd(&cnt[t * NPG + d], 1);
    recs[g * EPG + pos] = (u16)s;
  }
  for (int i = tid; i <= 6 * NPG; i += 256) rows[g * (6 * NPG + 1) + i] = ro[i];
}

__global__ void k_cvt(const float* __restrict__ src, u16* __restrict__ dst, int n) {
  int i = blockIdx.x * 256 + threadIdx.x;
  if (i < n) dst[i] = f2bf(src[i]);
}

__global__ void k_tcvt(const float* __restrict__ src, u16* __restrict__ dst, int R, int C) {
  int i = blockIdx.x * 256 + threadIdx.x;
  if (i < R * C) {
    int r = i / C, c = i - r * C;
    dst[c * R + r] = f2bf(src[i]);
  }
}

__global__ void k_cvt_weT(const float* __restrict__ W_edge, u16* __restrict__ WeT) {
  int i = blockIdx.x * 256 + threadIdx.x;
  if (i < 6 * 64 * 64) {
    int t = i >> 12, rem = i & 4095;
    int o = rem >> 6, k = rem & 63;
    WeT[i] = f2bf(W_edge[t * 4096 + k * 64 + o]);
  }
}

// ---------------- fused GGNN 5-step kernel (one block per graph) ----------------

__global__ void __launch_bounds__(512, 1) k_ggnn_steps(
    const float* __restrict__ feats,
    const u16* __restrict__ WeT, const float* __restrict__ b_edge,
    const u16* __restrict__ Wihb, const u16* __restrict__ Whhb,
    const float* __restrict__ gb_ih, const float* __restrict__ gb_hh,
    const u16* __restrict__ recs, const int* __restrict__ rows,
    float* __restrict__ h_out) {
  __shared__ float h_s[NPG * HSTR];      // 52,000 B
  __shared__ u16 hb_s[208 * WSTR];       // 29,952 B
  __shared__ u16 wh_s[208 * WSTR];       // 29,952 B
  __shared__ u16 rec_s[EPG];             //  6,400 B
  __shared__ int row_s[6 * NPG + 1];     //  4,804 B   -> total 123,108 B

  int g = blockIdx.x;
  int tid = threadIdx.x;
  int lane = tid & 63, w = tid >> 6;
  int m = lane & 15, quad = lane >> 4;

  for (int i = tid; i < NPG * 64; i += 512) {
    int n = i >> 6, d = i & 63;
    float v = feats[(size_t)g * NPG * 64 + i];
    h_s[n * HSTR + d] = v;
    hb_s[n * WSTR + d] = f2bf(v);
  }
  // zero pad rows 200..207 (keeps all MFMA inputs finite)
  for (int i = tid; i < 8 * WSTR; i += 512) {
    hb_s[NPG * WSTR + i] = 0;
    wh_s[NPG * WSTR + i] = 0;
  }
  {
    const u32* r32 = (const u32*)(recs + g * EPG);
    u32* rs32 = (u32*)rec_s;
    for (int i = tid; i < EPG / 2; i += 512) rs32[i] = r32[i];
  }
  for (int i = tid; i <= 6 * NPG; i += 512) row_s[i] = rows[g * (6 * NPG + 1) + i];

  float acc[25];
#pragma unroll
  for (int q = 0; q < 25; q++) acc[q] = 0.f;

  float bir[4], bhr[4], biz[4], bhz[4], bin_[4], bhn[4];
#pragma unroll
  for (int dq = 0; dq < 4; dq++) {
    int d = dq * 16 + m;
    bir[dq] = gb_ih[d];        bhr[dq] = gb_hh[d];
    biz[dq] = gb_ih[64 + d];   bhz[dq] = gb_hh[64 + d];
    bin_[dq] = gb_ih[128 + d]; bhn[dq] = gb_hh[128 + d];
  }

  for (int step = 0; step < NSTEPS; step++) {
    // ---- 6 phases: Wh(etype t) -> wh_s; CSR gather into acc regs ----
    for (int t = 0; t < 6; t++) {
      __syncthreads();  // prior readers of wh_s done
      for (int tile = w; tile < 13; tile += 8) {
        const u16* ap = hb_s + (tile * 16 + m) * WSTR + quad * 8;
        bf16x8 a0 = *(const bf16x8*)ap;
        bf16x8 a1 = *(const bf16x8*)(ap + 32);
#pragma unroll
        for (int ot = 0; ot < 4; ot++) {
          const u16* bp2 = WeT + ((t * 64 + ot * 16 + m) * 64) + quad * 8;
          bf16x8 b0 = *(const bf16x8*)bp2;
          bf16x8 b1 = *(const bf16x8*)(bp2 + 32);
          f32x4 c = {0.f, 0.f, 0.f, 0.f};
          c = __builtin_amdgcn_mfma_f32_16x16x32_bf16(a0, b0, c, 0, 0, 0);
          c = __builtin_amdgcn_mfma_f32_16x16x32_bf16(a1, b1, c, 0, 0, 0);
          float bias = b_edge[t * 64 + ot * 16 + m];
#pragma unroll
          for (int r = 0; r < 4; r++) {
            wh_s[(tile * 16 + quad * 4 + r) * WSTR + ot * 16 + m] = f2bf(c[r] + bias);
          }
        }
      }
      __syncthreads();
      const int* row = row_s + t * NPG;
      for (int q = 0; q < 25; q++) {
        int n = q * 8 + w;
        int rs = row[n], re = row[n + 1];
        float r = 0.f;
        int e = rs;
        for (; e + 2 <= re; e += 2) {
          int s0 = rec_s[e], s1 = rec_s[e + 1];
          r += bf2f(wh_s[s0 * WSTR + lane]) + bf2f(wh_s[s1 * WSTR + lane]);
        }
        for (; e < re; e++) r += bf2f(wh_s[(int)rec_s[e] * WSTR + lane]);
        acc[q] += r;
      }
    }
    __syncthreads();  // all scatter reads of wh_s done
    // ---- ab into wh_s (reuse) ----
    for (int q = 0; q < 25; q++) {
      int n = q * 8 + w;
      wh_s[n * WSTR + lane] = f2bf(acc[q]);
      acc[q] = 0.f;
    }
    __syncthreads();
    // ---- GRU (register accumulators; epilogue writes h_s/hb_s own rows) ----
    for (int tile = w; tile < 13; tile += 8) {
      const u16* aap = wh_s + (tile * 16 + m) * WSTR + quad * 8;
      const u16* ahp = hb_s + (tile * 16 + m) * WSTR + quad * 8;
      bf16x8 aa0 = *(const bf16x8*)aap;
      bf16x8 aa1 = *(const bf16x8*)(aap + 32);
      bf16x8 ah0 = *(const bf16x8*)ahp;
      bf16x8 ah1 = *(const bf16x8*)(ahp + 32);
      f32x4 ci[12], ch[12];
#pragma unroll
      for (int jt = 0; jt < 12; jt++) {
        const u16* bip = Wihb + (jt * 16 + m) * 64 + quad * 8;
        const u16* bhp = Whhb + (jt * 16 + m) * 64 + quad * 8;
        bf16x8 bi0 = *(const bf16x8*)bip;
        bf16x8 bi1 = *(const bf16x8*)(bip + 32);
        bf16x8 bh0 = *(const bf16x8*)bhp;
        bf16x8 bh1 = *(const bf16x8*)(bhp + 32);
        f32x4 z4 = {0.f, 0.f, 0.f, 0.f};
        ci[jt] = __builtin_amdgcn_mfma_f32_16x16x32_bf16(aa0, bi0, z4, 0, 0, 0);
        ci[jt] = __builtin_amdgcn_mfma_f32_16x16x32_bf16(aa1, bi1, ci[jt], 0, 0, 0);
        ch[jt] = __builtin_amdgcn_mfma_f32_16x16x32_bf16(ah0, bh0, z4, 0, 0, 0);
        ch[jt] = __builtin_amdgcn_mfma_f32_16x16x32_bf16(ah1, bh1, ch[jt], 0, 0, 0);
      }
#pragma unroll
      for (int r = 0; r < 4; r++) {
        int node = tile * 16 + quad * 4 + r;
        if (node < NPG) {
#pragma unroll
          for (int dq = 0; dq < 4; dq++) {
            int d = dq * 16 + m;
            float rr = sigmf(ci[dq][r] + ch[dq][r] + bir[dq] + bhr[dq]);
            float zz = sigmf(ci[4 + dq][r] + ch[4 + dq][r] + biz[dq] + bhz[dq]);
            float nn = tanhf(ci[8 + dq][r] + bin_[dq] + rr * (ch[8 + dq][r] + bhn[dq]));
            float hv = h_s[node * HSTR + d];
            float hn = (1.0f - zz) * nn + zz * hv;
            h_s[node * HSTR + d] = hn;
            hb_s[node * WSTR + d] = f2bf(hn);
          }
        }
      }
    }
  }
  __syncthreads();
  // write final h to global (coalesced)
  for (int i = tid; i < NPG * 64; i += 512) {
    int n = i >> 6, d = i & 63;
    h_out[(size_t)g * NPG * 64 + i] = h_s[n * HSTR + d];
  }
}

// ---------------- Set2Set (proven round-8 version) ----------------

__global__ void __launch_bounds__(512, 1) k_set2set(
    const float* __restrict__ feat,
    const u16* __restrict__ WTih0b, const u16* __restrict__ WThh0b,
    const u16* __restrict__ WTih1b, const u16* __restrict__ WThh1b,
    const u16* __restrict__ WTih2b, const u16* __restrict__ WThh2b,
    const float* __restrict__ b_ih0, const float* __restrict__ b_hh0,
    const float* __restrict__ b_ih1, const float* __restrict__ b_hh1,
    const float* __restrict__ b_ih2, const float* __restrict__ b_hh2,
    const float* __restrict__ Wp, const float* __restrict__ bp,
    float* __restrict__ out) {
  __shared__ __align__(16) float feat_s[NPG * 64];
  __shared__ float qstar[128];
  __shared__ float xbuf[64];
  __shared__ float hs_s[3][64];
  __shared__ float cs_s[3][64];
  __shared__ float gates[256];
  __shared__ float gpart[2 * 256];
  __shared__ float e_s[NPG];
  __shared__ float red[8][64];
  __shared__ float scal[2];
  int tid = threadIdx.x;
  int g = blockIdx.x;
  int lane = tid & 63, wid = tid >> 6;
  int j = tid & 255, part = tid >> 8;
  for (int i = tid; i < NPG * 64; i += 512) feat_s[i] = feat[(size_t)g * NPG * 64 + i];
  if (tid < 128) qstar[tid] = 0.f;
  if (tid < 64) {
    xbuf[tid] = 0.f;
    for (int l = 0; l < 3; l++) { hs_s[l][tid] = 0.f; cs_s[l][tid] = 0.f; }
  }
  __syncthreads();
  for (int it = 0; it < NITERS; it++) {
    {
      float acc = 0.f;
      if (part == 0) {
#pragma unroll 8
        for (int k = 0; k < 96; k++) acc += qstar[k] * bf2f(WTih0b[k * 256 + j]);
      } else {
#pragma unroll 8
        for (int k = 96; k < 128; k++) acc += qstar[k] * bf2f(WTih0b[k * 256 + j]);
#pragma unroll 8
        for (int k = 0; k < 64; k++) acc += hs_s[0][k] * bf2f(WThh0b[k * 256 + j]);
      }
      gpart[part * 256 + j] = acc;
    }
    __syncthreads();
    if (tid < 256) gates[tid] = gpart[tid] + gpart[256 + tid] + b_ih0[tid] + b_hh0[tid];
    __syncthreads();
    if (tid < 64) {
      float c = sigmf(gates[64 + tid]) * cs_s[0][tid] + sigmf(gates[tid]) * tanhf(gates[128 + tid]);
      float x = sigmf(gates[192 + tid]) * tanhf(c);
      cs_s[0][tid] = c; hs_s[0][tid] = x; xbuf[tid] = x;
    }
    __syncthreads();
    for (int l = 1; l < 3; l++) {
      const u16* Wi = (l == 1) ? WTih1b : WTih2b;
      const u16* Wh = (l == 1) ? WThh1b : WThh2b;
      const float* bi = (l == 1) ? b_ih1 : b_ih2;
      const float* bh = (l == 1) ? b_hh1 : b_hh2;
      const u16* W = part ? Wh : Wi;
      const float* xv = part ? hs_s[l] : xbuf;
      float acc = 0.f;
#pragma unroll 8
      for (int k = 0; k < 64; k++) acc += xv[k] * bf2f(W[k * 256 + j]);
      gpart[part * 256 + j] = acc;
      __syncthreads();
      if (tid < 256) gates[tid] = gpart[tid] + gpart[256 + tid] + bi[tid] + bh[tid];
      __syncthreads();
      if (tid < 64) {
        float c = sigmf(gates[64 + tid]) * cs_s[l][tid] + sigmf(gates[tid]) * tanhf(gates[128 + tid]);
        float x = sigmf(gates[192 + tid]) * tanhf(c);
        cs_s[l][tid] = c; hs_s[l][tid] = x; xbuf[tid] = x;
      }
      __syncthreads();
    }
    for (int n = wid; n < NPG; n += 8) {
      float v = feat_s[n * 64 + lane] * xbuf[lane];
      for (int off = 32; off > 0; off >>= 1) v += __shfl_down(v, off);
      if (lane == 0) e_s[n] = v;
    }
    __syncthreads();
    if (tid < 64) {
      float mx = -1e30f;
      for (int n = lane; n < NPG; n += 64) mx = fmaxf(mx, e_s[n]);
      for (int off = 32; off > 0; off >>= 1) mx = fmaxf(mx, __shfl_down(mx, off));
      mx = __shfl(mx, 0);
      float ssum = 0.f;
      for (int n = lane; n < NPG; n += 64) {
        float ex = __expf(e_s[n] - mx);
        e_s[n] = ex;
        ssum += ex;
      }
      for (int off = 32; off > 0; off >>= 1) ssum += __shfl_down(ssum, off);
      if (lane == 0) scal[0] = ssum;
    }
    __syncthreads();
    float denom = scal[0];
    {
      float r = 0.f;
      for (int n = wid; n < NPG; n += 8) r += feat_s[n * 64 + lane] * e_s[n];
      red[wid][lane] = r;
    }
    __syncthreads();
    if (tid < 64) {
      float ro = 0.f;
#pragma unroll
      for (int ww = 0; ww < 8; ww++) ro += red[ww][lane];
      qstar[lane] = xbuf[lane];
      qstar[64 + lane] = ro / denom;
    }
    __syncthreads();
  }
  if (tid < 3) {
    float s = bp[tid];
    for (int k = 0; k < 128; k++) s += qstar[k] * Wp[tid * 128 + k];
    out[g * 3 + tid] = s;
  }
}

// ---------------- host ----------------

extern "C" void kernel_launch(void* const* d_in, const int* in_sizes, int n_in,
                              void* d_out, int out_size, void* d_ws, size_t ws_size,
                              hipStream_t stream) {
  const float* feats  = (const float*)d_in[0];
  const float* W_edge = (const float*)d_in[1];
  const float* b_edge = (const float*)d_in[2];
  const float* gWih   = (const float*)d_in[3];
  const float* gWhh   = (const float*)d_in[4];
  const float* gbih   = (const float*)d_in[5];
  const float* gbhh   = (const float*)d_in[6];
  const float* lWi0   = (const float*)d_in[7];
  const float* lWh0   = (const float*)d_in[8];
  const float* lbi0   = (const float*)d_in[9];
  const float* lbh0   = (const float*)d_in[10];
  const float* lWi1   = (const float*)d_in[11];
  const float* lWh1   = (const float*)d_in[12];
  const float* lbi1   = (const float*)d_in[13];
  const float* lbh1   = (const float*)d_in[14];
  const float* lWi2   = (const float*)d_in[15];
  const float* lWh2   = (const float*)d_in[16];
  const float* lbi2   = (const float*)d_in[17];
  const float* lbh2   = (const float*)d_in[18];
  const float* Wp     = (const float*)d_in[19];
  const float* bp     = (const float*)d_in[20];
  const int* src      = (const int*)d_in[21];
  const int* dst      = (const int*)d_in[22];
  const int* ety      = (const int*)d_in[23];
  float* out = (float*)d_out;

  char* ws = (char*)d_ws;
  u16* recs   = (u16*)ws;                        //  [0, 2,048,000)
  int* rows   = (int*)(ws + 2048000);            //  [2,048,000, 3,585,280)
  u16* WeTb   = (u16*)(ws + 3585280);            //  +49,152  -> 3,634,432
  u16* Wihb   = (u16*)(ws + 3634432);            //  +24,576  -> 3,659,008
  u16* Whhb   = (u16*)(ws + 3659008);            //  +24,576  -> 3,683,584
  u16* WTih0b = (u16*)(ws + 3683584);            //  +65,536  -> 3,749,120
  u16* WThh0b = WTih0b + 32768;                  //  +32,768  -> 3,781,888
  u16* WTih1b = WThh0b + 16384;                  //  +32,768  -> 3,814,656
  u16* WThh1b = WTih1b + 16384;                  //  +32,768  -> 3,847,424
  u16* WTih2b = WThh1b + 16384;                  //  +32,768  -> 3,880,192
  u16* WThh2b = WTih2b + 16384;                  //  +32,768  -> 3,912,960
  float* hfin = (float*)(ws + 4194304);          //  [4,194,304, 20,578,304) — clear of weights

  k_csr6<<<NGRAPH, 256, 0, stream>>>(src, dst, ety, recs, rows);
  k_cvt_weT<<<96, 256, 0, stream>>>(W_edge, WeTb);
  k_cvt<<<48, 256, 0, stream>>>(gWih, Wihb, 12288);
  k_cvt<<<48, 256, 0, stream>>>(gWhh, Whhb, 12288);
  k_tcvt<<<128, 256, 0, stream>>>(lWi0, WTih0b, 256, 128);
  k_tcvt<<<64, 256, 0, stream>>>(lWh0, WThh0b, 256, 64);
  k_tcvt<<<64, 256, 0, stream>>>(lWi1, WTih1b, 256, 64);
  k_tcvt<<<64, 256, 0, stream>>>(lWh1, WThh1b, 256, 64);
  k_tcvt<<<64, 256, 0, stream>>>(lWi2, WTih2b, 256, 64);
  k_tcvt<<<64, 256, 0, stream>>>(lWh2, WThh2b, 256, 64);

  k_ggnn_steps<<<NGRAPH, 512, 0, stream>>>(feats, WeTb, b_edge, Wihb, Whhb,
                                           gbih, gbhh, recs, rows, hfin);
  k_set2set<<<NGRAPH, 512, 0, stream>>>(hfin, WTih0b, WThh0b, WTih1b, WThh1b,
                                        WTih2b, WThh2b, lbi0, lbh0, lbi1, lbh1,
                                        lbi2, lbh2, Wp, bp, out);
}

// Round 12
// 1240.103 us; speedup vs baseline: 1.0404x; 1.0142x over previous
//
#include <hip/hip_runtime.h>

typedef unsigned short u16;
typedef unsigned int u32;

#define N_NODES 64000
#define DIM 64
#define NGRAPH 320
#define NPG 200
#define NEDGE 1024000
#define EPG 3200
#define NSTEPS 5
#define NITERS 6
#define WSTR 72   // u16 row stride for bf16 tiles (bank-conflict padding)
#define HSTR 65   // float row stride for h_s

typedef __attribute__((ext_vector_type(8))) short bf16x8;
typedef __attribute__((ext_vector_type(4))) float f32x4;

__device__ __forceinline__ float bf2f(u16 u) {
  u32 x = ((u32)u) << 16;
  float f;
  __builtin_memcpy(&f, &x, 4);
  return f;
}
__device__ __forceinline__ u16 f2bf(float f) {
  u32 x;
  __builtin_memcpy(&x, &f, 4);
  x = (x + 0x7FFFu + ((x >> 16) & 1u)) >> 16;
  return (u16)x;
}
__device__ __forceinline__ float sigmf(float x) { return 1.0f / (1.0f + __expf(-x)); }

// ---------------- prep kernels ----------------

__global__ void __launch_bounds__(256) k_csr6(const int* __restrict__ src,
                                              const int* __restrict__ dst,
                                              const int* __restrict__ ety,
                                              u16* __restrict__ recs,
                                              int* __restrict__ rows) {
  __shared__ int cnt[6 * NPG];
  __shared__ int ro[6 * NPG + 1];
  int g = blockIdx.x, tid = threadIdx.x;
  int base = g * NPG;
  for (int i = tid; i < 6 * NPG; i += 256) cnt[i] = 0;
  __syncthreads();
  for (int e = tid; e < EPG; e += 256) {
    int d = dst[g * EPG + e] - base;
    int t = ety[g * EPG + e];
    atomicAdd(&cnt[t * NPG + d], 1);
  }
  __syncthreads();
  if (tid == 0) {
    int s = 0;
    for (int i = 0; i < 6 * NPG; i++) { ro[i] = s; s += cnt[i]; }
    ro[6 * NPG] = s;  // == EPG
  }
  __syncthreads();
  for (int i = tid; i < 6 * NPG; i += 256) cnt[i] = ro[i];
  __syncthreads();
  for (int e = tid; e < EPG; e += 256) {
    int d = dst[g * EPG + e] - base;
    int t = ety[g * EPG + e];
    int s = src[g * EPG + e] - base;
    int pos = atomicAdd(&cnt[t * NPG + d], 1);
    recs[g * EPG + pos] = (u16)s;
  }
  for (int i = tid; i <= 6 * NPG; i += 256) rows[g * (6 * NPG + 1) + i] = ro[i];
}

__global__ void k_cvt(const float* __restrict__ src, u16* __restrict__ dst, int n) {
  int i = blockIdx.x * 256 + threadIdx.x;
  if (i < n) dst[i] = f2bf(src[i]);
}

__global__ void k_tcvt(const float* __restrict__ src, u16* __restrict__ dst, int R, int C) {
  int i = blockIdx.x * 256 + threadIdx.x;
  if (i < R * C) {
    int r = i / C, c = i - r * C;
    dst[c * R + r] = f2bf(src[i]);
  }
}

__global__ void k_cvt_weT(const float* __restrict__ W_edge, u16* __restrict__ WeT) {
  int i = blockIdx.x * 256 + threadIdx.x;
  if (i < 6 * 64 * 64) {
    int t = i >> 12, rem = i & 4095;
    int o = rem >> 6, k = rem & 63;
    WeT[i] = f2bf(W_edge[t * 4096 + k * 64 + o]);
  }
}

// ---------------- fused GGNN 5-step kernel (one block per graph) ----------------
// GRU is phase-split by gate group (r/z/n) to keep live VGPRs < 128 (the
// allocator caps 512-thread kernels at 128; rounds 9/11 spilled ~290MB).

__global__ void __launch_bounds__(512, 1) k_ggnn_steps(
    const float* __restrict__ feats,
    const u16* __restrict__ WeT, const float* __restrict__ b_edge,
    const u16* __restrict__ Wihb, const u16* __restrict__ Whhb,
    const float* __restrict__ gb_ih, const float* __restrict__ gb_hh,
    const u16* __restrict__ recs, const int* __restrict__ rows,
    float* __restrict__ h_out) {
  __shared__ float h_s[NPG * HSTR];      // 52,000 B
  __shared__ u16 hb_s[208 * WSTR];       // 29,952 B
  __shared__ u16 wh_s[208 * WSTR];       // 29,952 B
  __shared__ u16 rec_s[EPG];             //  6,400 B
  __shared__ int row_s[6 * NPG + 1];     //  4,804 B   -> total 123,108 B

  int g = blockIdx.x;
  int tid = threadIdx.x;
  int lane = tid & 63, w = tid >> 6;
  int m = lane & 15, quad = lane >> 4;

  for (int i = tid; i < NPG * 64; i += 512) {
    int n = i >> 6, d = i & 63;
    float v = feats[(size_t)g * NPG * 64 + i];
    h_s[n * HSTR + d] = v;
    hb_s[n * WSTR + d] = f2bf(v);
  }
  for (int i = tid; i < 8 * WSTR; i += 512) {
    hb_s[NPG * WSTR + i] = 0;
    wh_s[NPG * WSTR + i] = 0;
  }
  {
    const u32* r32 = (const u32*)(recs + g * EPG);
    u32* rs32 = (u32*)rec_s;
    for (int i = tid; i < EPG / 2; i += 512) rs32[i] = r32[i];
  }
  for (int i = tid; i <= 6 * NPG; i += 512) row_s[i] = rows[g * (6 * NPG + 1) + i];

  float acc[25];
#pragma unroll
  for (int q = 0; q < 25; q++) acc[q] = 0.f;

  // folded biases per lane (d = dq*16 + m): r/z use (b_ih+b_hh); n keeps both
  float br_[4], bz_[4], bin_[4], bhn_[4];
#pragma unroll
  for (int dq = 0; dq < 4; dq++) {
    int d = dq * 16 + m;
    br_[dq] = gb_ih[d] + gb_hh[d];
    bz_[dq] = gb_ih[64 + d] + gb_hh[64 + d];
    bin_[dq] = gb_ih[128 + d];
    bhn_[dq] = gb_hh[128 + d];
  }

  for (int step = 0; step < NSTEPS; step++) {
    // ---- 6 phases: Wh(etype t) -> wh_s; CSR gather into acc regs ----
    for (int t = 0; t < 6; t++) {
      __syncthreads();  // prior readers of wh_s done
      for (int tile = w; tile < 13; tile += 8) {
        const u16* ap = hb_s + (tile * 16 + m) * WSTR + quad * 8;
        bf16x8 a0 = *(const bf16x8*)ap;
        bf16x8 a1 = *(const bf16x8*)(ap + 32);
#pragma unroll
        for (int ot = 0; ot < 4; ot++) {
          const u16* bp2 = WeT + ((t * 64 + ot * 16 + m) * 64) + quad * 8;
          bf16x8 b0 = *(const bf16x8*)bp2;
          bf16x8 b1 = *(const bf16x8*)(bp2 + 32);
          f32x4 c = {0.f, 0.f, 0.f, 0.f};
          c = __builtin_amdgcn_mfma_f32_16x16x32_bf16(a0, b0, c, 0, 0, 0);
          c = __builtin_amdgcn_mfma_f32_16x16x32_bf16(a1, b1, c, 0, 0, 0);
          float bias = b_edge[t * 64 + ot * 16 + m];
#pragma unroll
          for (int r = 0; r < 4; r++) {
            wh_s[(tile * 16 + quad * 4 + r) * WSTR + ot * 16 + m] = f2bf(c[r] + bias);
          }
        }
      }
      __syncthreads();
      const int* row = row_s + t * NPG;
      for (int q = 0; q < 25; q++) {
        int n = q * 8 + w;
        int rs = row[n], re = row[n + 1];
        float r = 0.f;
        int e = rs;
        for (; e + 2 <= re; e += 2) {
          int s0 = rec_s[e], s1 = rec_s[e + 1];
          r += bf2f(wh_s[s0 * WSTR + lane]) + bf2f(wh_s[s1 * WSTR + lane]);
        }
        for (; e < re; e++) r += bf2f(wh_s[(int)rec_s[e] * WSTR + lane]);
        acc[q] += r;
      }
    }
    __syncthreads();  // all scatter reads of wh_s done
    // ---- ab into wh_s (reuse) ----
    for (int q = 0; q < 25; q++) {
      int n = q * 8 + w;
      wh_s[n * WSTR + lane] = f2bf(acc[q]);
      acc[q] = 0.f;
    }
    __syncthreads();
    // ---- GRU, phase-split by gate group: r -> z -> n ----
    for (int tile = w; tile < 13; tile += 8) {
      const u16* aap = wh_s + (tile * 16 + m) * WSTR + quad * 8;
      const u16* ahp = hb_s + (tile * 16 + m) * WSTR + quad * 8;
      bf16x8 aa0 = *(const bf16x8*)aap;
      bf16x8 aa1 = *(const bf16x8*)(aap + 32);
      bf16x8 ah0 = *(const bf16x8*)ahp;
      bf16x8 ah1 = *(const bf16x8*)(ahp + 32);
      float rr[16], zz[16];  // [r*4+dq]
      {
        f32x4 ci[4], ch[4];
#pragma unroll
        for (int jt = 0; jt < 4; jt++) {
          const u16* bip = Wihb + (jt * 16 + m) * 64 + quad * 8;
          const u16* bhp = Whhb + (jt * 16 + m) * 64 + quad * 8;
          bf16x8 bi0 = *(const bf16x8*)bip;
          bf16x8 bi1 = *(const bf16x8*)(bip + 32);
          bf16x8 bh0 = *(const bf16x8*)bhp;
          bf16x8 bh1 = *(const bf16x8*)(bhp + 32);
          f32x4 z4 = {0.f, 0.f, 0.f, 0.f};
          ci[jt] = __builtin_amdgcn_mfma_f32_16x16x32_bf16(aa0, bi0, z4, 0, 0, 0);
          ci[jt] = __builtin_amdgcn_mfma_f32_16x16x32_bf16(aa1, bi1, ci[jt], 0, 0, 0);
          ch[jt] = __builtin_amdgcn_mfma_f32_16x16x32_bf16(ah0, bh0, z4, 0, 0, 0);
          ch[jt] = __builtin_amdgcn_mfma_f32_16x16x32_bf16(ah1, bh1, ch[jt], 0, 0, 0);
        }
#pragma unroll
        for (int r = 0; r < 4; r++)
#pragma unroll
          for (int dq = 0; dq < 4; dq++)
            rr[r * 4 + dq] = sigmf(ci[dq][r] + ch[dq][r] + br_[dq]);
      }
      {
        f32x4 ci[4], ch[4];
#pragma unroll
        for (int jt = 0; jt < 4; jt++) {
          const u16* bip = Wihb + ((4 + jt) * 16 + m) * 64 + quad * 8;
          const u16* bhp = Whhb + ((4 + jt) * 16 + m) * 64 + quad * 8;
          bf16x8 bi0 = *(const bf16x8*)bip;
          bf16x8 bi1 = *(const bf16x8*)(bip + 32);
          bf16x8 bh0 = *(const bf16x8*)bhp;
          bf16x8 bh1 = *(const bf16x8*)(bhp + 32);
          f32x4 z4 = {0.f, 0.f, 0.f, 0.f};
          ci[jt] = __builtin_amdgcn_mfma_f32_16x16x32_bf16(aa0, bi0, z4, 0, 0, 0);
          ci[jt] = __builtin_amdgcn_mfma_f32_16x16x32_bf16(aa1, bi1, ci[jt], 0, 0, 0);
          ch[jt] = __builtin_amdgcn_mfma_f32_16x16x32_bf16(ah0, bh0, z4, 0, 0, 0);
          ch[jt] = __builtin_amdgcn_mfma_f32_16x16x32_bf16(ah1, bh1, ch[jt], 0, 0, 0);
        }
#pragma unroll
        for (int r = 0; r < 4; r++)
#pragma unroll
          for (int dq = 0; dq < 4; dq++)
            zz[r * 4 + dq] = sigmf(ci[dq][r] + ch[dq][r] + bz_[dq]);
      }
      {
        f32x4 ci[4], ch[4];
#pragma unroll
        for (int jt = 0; jt < 4; jt++) {
          const u16* bip = Wihb + ((8 + jt) * 16 + m) * 64 + quad * 8;
          const u16* bhp = Whhb + ((8 + jt) * 16 + m) * 64 + quad * 8;
          bf16x8 bi0 = *(const bf16x8*)bip;
          bf16x8 bi1 = *(const bf16x8*)(bip + 32);
          bf16x8 bh0 = *(const bf16x8*)bhp;
          bf16x8 bh1 = *(const bf16x8*)(bhp + 32);
          f32x4 z4 = {0.f, 0.f, 0.f, 0.f};
          ci[jt] = __builtin_amdgcn_mfma_f32_16x16x32_bf16(aa0, bi0, z4, 0, 0, 0);
          ci[jt] = __builtin_amdgcn_mfma_f32_16x16x32_bf16(aa1, bi1, ci[jt], 0, 0, 0);
          ch[jt] = __builtin_amdgcn_mfma_f32_16x16x32_bf16(ah0, bh0, z4, 0, 0, 0);
          ch[jt] = __builtin_amdgcn_mfma_f32_16x16x32_bf16(ah1, bh1, ch[jt], 0, 0, 0);
        }
#pragma unroll
        for (int r = 0; r < 4; r++) {
          int node = tile * 16 + quad * 4 + r;
          if (node < NPG) {
#pragma unroll
            for (int dq = 0; dq < 4; dq++) {
              int d = dq * 16 + m;
              float nn = tanhf(ci[dq][r] + bin_[dq] +
                               rr[r * 4 + dq] * (ch[dq][r] + bhn_[dq]));
              float hv = h_s[node * HSTR + d];
              float z1 = zz[r * 4 + dq];
              float hn = (1.0f - z1) * nn + z1 * hv;
              h_s[node * HSTR + d] = hn;
              hb_s[node * WSTR + d] = f2bf(hn);
            }
          }
        }
      }
    }
  }
  __syncthreads();
  for (int i = tid; i < NPG * 64; i += 512) {
    int n = i >> 6, d = i & 63;
    h_out[(size_t)g * NPG * 64 + i] = h_s[n * HSTR + d];
  }
}

// ---------------- Set2Set (proven round-8 version) ----------------

__global__ void __launch_bounds__(512, 1) k_set2set(
    const float* __restrict__ feat,
    const u16* __restrict__ WTih0b, const u16* __restrict__ WThh0b,
    const u16* __restrict__ WTih1b, const u16* __restrict__ WThh1b,
    const u16* __restrict__ WTih2b, const u16* __restrict__ WThh2b,
    const float* __restrict__ b_ih0, const float* __restrict__ b_hh0,
    const float* __restrict__ b_ih1, const float* __restrict__ b_hh1,
    const float* __restrict__ b_ih2, const float* __restrict__ b_hh2,
    const float* __restrict__ Wp, const float* __restrict__ bp,
    float* __restrict__ out) {
  __shared__ __align__(16) float feat_s[NPG * 64];
  __shared__ float qstar[128];
  __shared__ float xbuf[64];
  __shared__ float hs_s[3][64];
  __shared__ float cs_s[3][64];
  __shared__ float gates[256];
  __shared__ float gpart[2 * 256];
  __shared__ float e_s[NPG];
  __shared__ float red[8][64];
  __shared__ float scal[2];
  int tid = threadIdx.x;
  int g = blockIdx.x;
  int lane = tid & 63, wid = tid >> 6;
  int j = tid & 255, part = tid >> 8;
  for (int i = tid; i < NPG * 64; i += 512) feat_s[i] = feat[(size_t)g * NPG * 64 + i];
  if (tid < 128) qstar[tid] = 0.f;
  if (tid < 64) {
    xbuf[tid] = 0.f;
    for (int l = 0; l < 3; l++) { hs_s[l][tid] = 0.f; cs_s[l][tid] = 0.f; }
  }
  __syncthreads();
  for (int it = 0; it < NITERS; it++) {
    {
      float acc = 0.f;
      if (part == 0) {
#pragma unroll 8
        for (int k = 0; k < 96; k++) acc += qstar[k] * bf2f(WTih0b[k * 256 + j]);
      } else {
#pragma unroll 8
        for (int k = 96; k < 128; k++) acc += qstar[k] * bf2f(WTih0b[k * 256 + j]);
#pragma unroll 8
        for (int k = 0; k < 64; k++) acc += hs_s[0][k] * bf2f(WThh0b[k * 256 + j]);
      }
      gpart[part * 256 + j] = acc;
    }
    __syncthreads();
    if (tid < 256) gates[tid] = gpart[tid] + gpart[256 + tid] + b_ih0[tid] + b_hh0[tid];
    __syncthreads();
    if (tid < 64) {
      float c = sigmf(gates[64 + tid]) * cs_s[0][tid] + sigmf(gates[tid]) * tanhf(gates[128 + tid]);
      float x = sigmf(gates[192 + tid]) * tanhf(c);
      cs_s[0][tid] = c; hs_s[0][tid] = x; xbuf[tid] = x;
    }
    __syncthreads();
    for (int l = 1; l < 3; l++) {
      const u16* Wi = (l == 1) ? WTih1b : WTih2b;
      const u16* Wh = (l == 1) ? WThh1b : WThh2b;
      const float* bi = (l == 1) ? b_ih1 : b_ih2;
      const float* bh = (l == 1) ? b_hh1 : b_hh2;
      const u16* W = part ? Wh : Wi;
      const float* xv = part ? hs_s[l] : xbuf;
      float acc = 0.f;
#pragma unroll 8
      for (int k = 0; k < 64; k++) acc += xv[k] * bf2f(W[k * 256 + j]);
      gpart[part * 256 + j] = acc;
      __syncthreads();
      if (tid < 256) gates[tid] = gpart[tid] + gpart[256 + tid] + bi[tid] + bh[tid];
      __syncthreads();
      if (tid < 64) {
        float c = sigmf(gates[64 + tid]) * cs_s[l][tid] + sigmf(gates[tid]) * tanhf(gates[128 + tid]);
        float x = sigmf(gates[192 + tid]) * tanhf(c);
        cs_s[l][tid] = c; hs_s[l][tid] = x; xbuf[tid] = x;
      }
      __syncthreads();
    }
    for (int n = wid; n < NPG; n += 8) {
      float v = feat_s[n * 64 + lane] * xbuf[lane];
      for (int off = 32; off > 0; off >>= 1) v += __shfl_down(v, off);
      if (lane == 0) e_s[n] = v;
    }
    __syncthreads();
    if (tid < 64) {
      float mx = -1e30f;
      for (int n = lane; n < NPG; n += 64) mx = fmaxf(mx, e_s[n]);
      for (int off = 32; off > 0; off >>= 1) mx = fmaxf(mx, __shfl_down(mx, off));
      mx = __shfl(mx, 0);
      float ssum = 0.f;
      for (int n = lane; n < NPG; n += 64) {
        float ex = __expf(e_s[n] - mx);
        e_s[n] = ex;
        ssum += ex;
      }
      for (int off = 32; off > 0; off >>= 1) ssum += __shfl_down(ssum, off);
      if (lane == 0) scal[0] = ssum;
    }
    __syncthreads();
    float denom = scal[0];
    {
      float r = 0.f;
      for (int n = wid; n < NPG; n += 8) r += feat_s[n * 64 + lane] * e_s[n];
      red[wid][lane] = r;
    }
    __syncthreads();
    if (tid < 64) {
      float ro = 0.f;
#pragma unroll
      for (int ww = 0; ww < 8; ww++) ro += red[ww][lane];
      qstar[lane] = xbuf[lane];
      qstar[64 + lane] = ro / denom;
    }
    __syncthreads();
  }
  if (tid < 3) {
    float s = bp[tid];
    for (int k = 0; k < 128; k++) s += qstar[k] * Wp[tid * 128 + k];
    out[g * 3 + tid] = s;
  }
}

// ---------------- host ----------------

extern "C" void kernel_launch(void* const* d_in, const int* in_sizes, int n_in,
                              void* d_out, int out_size, void* d_ws, size_t ws_size,
                              hipStream_t stream) {
  const float* feats  = (const float*)d_in[0];
  const float* W_edge = (const float*)d_in[1];
  const float* b_edge = (const float*)d_in[2];
  const float* gWih   = (const float*)d_in[3];
  const float* gWhh   = (const float*)d_in[4];
  const float* gbih   = (const float*)d_in[5];
  const float* gbhh   = (const float*)d_in[6];
  const float* lWi0   = (const float*)d_in[7];
  const float* lWh0   = (const float*)d_in[8];
  const float* lbi0   = (const float*)d_in[9];
  const float* lbh0   = (const float*)d_in[10];
  const float* lWi1   = (const float*)d_in[11];
  const float* lWh1   = (const float*)d_in[12];
  const float* lbi1   = (const float*)d_in[13];
  const float* lbh1   = (const float*)d_in[14];
  const float* lWi2   = (const float*)d_in[15];
  const float* lWh2   = (const float*)d_in[16];
  const float* lbi2   = (const float*)d_in[17];
  const float* lbh2   = (const float*)d_in[18];
  const float* Wp     = (const float*)d_in[19];
  const float* bp     = (const float*)d_in[20];
  const int* src      = (const int*)d_in[21];
  const int* dst      = (const int*)d_in[22];
  const int* ety      = (const int*)d_in[23];
  float* out = (float*)d_out;

  char* ws = (char*)d_ws;
  u16* recs   = (u16*)ws;                        //  [0, 2,048,000)
  int* rows   = (int*)(ws + 2048000);            //  [2,048,000, 3,585,280)
  u16* WeTb   = (u16*)(ws + 3585280);            //  +49,152  -> 3,634,432
  u16* Wihb   = (u16*)(ws + 3634432);            //  +24,576  -> 3,659,008
  u16* Whhb   = (u16*)(ws + 3659008);            //  +24,576  -> 3,683,584
  u16* WTih0b = (u16*)(ws + 3683584);            //  +65,536  -> 3,749,120
  u16* WThh0b = WTih0b + 32768;
  u16* WTih1b = WThh0b + 16384;
  u16* WThh1b = WTih1b + 16384;
  u16* WTih2b = WThh1b + 16384;
  u16* WThh2b = WTih2b + 16384;                  //  ends 3,912,960
  float* hfin = (float*)(ws + 4194304);          //  clear of weights

  k_csr6<<<NGRAPH, 256, 0, stream>>>(src, dst, ety, recs, rows);
  k_cvt_weT<<<96, 256, 0, stream>>>(W_edge, WeTb);
  k_cvt<<<48, 256, 0, stream>>>(gWih, Wihb, 12288);
  k_cvt<<<48, 256, 0, stream>>>(gWhh, Whhb, 12288);
  k_tcvt<<<128, 256, 0, stream>>>(lWi0, WTih0b, 256, 128);
  k_tcvt<<<64, 256, 0, stream>>>(lWh0, WThh0b, 256, 64);
  k_tcvt<<<64, 256, 0, stream>>>(lWi1, WTih1b, 256, 64);
  k_tcvt<<<64, 256, 0, stream>>>(lWh1, WThh1b, 256, 64);
  k_tcvt<<<64, 256, 0, stream>>>(lWi2, WTih2b, 256, 64);
  k_tcvt<<<64, 256, 0, stream>>>(lWh2, WThh2b, 256, 64);

  k_ggnn_steps<<<NGRAPH, 512, 0, stream>>>(feats, WeTb, b_edge, Wihb, Whhb,
                                           gbih, gbhh, recs, rows, hfin);
  k_set2set<<<NGRAPH, 512, 0, stream>>>(hfin, WTih0b, WThh0b, WTih1b, WThh1b,
                                        WTih2b, WThh2b, lbi0, lbh0, lbi1, lbh1,
                                        lbi2, lbh2, Wp, bp, out);
}